// Round 1
// baseline (377.355 us; speedup 1.0000x reference)
//
#include <hip/hip_runtime.h>

typedef __bf16 bf16;
typedef __bf16 bf16x8 __attribute__((ext_vector_type(8)));
typedef __bf16 bf16x4 __attribute__((ext_vector_type(4)));
typedef float  f32x4  __attribute__((ext_vector_type(4)));

#define NND   2048      // nodes
#define DIMD  16        // embedding dim
#define NBB   8         // batch
#define CCC   66        // C_in + H
#define KITOT 198       // 3*66
#define NPADC 576       // padded panel rows (>= 528, mult of 64)

// ---------------------------------------------------------------
// K1: S = softmax(relu(E E^T)) rows, bf16 out. One block per row.
// ---------------------------------------------------------------
__global__ __launch_bounds__(256)
void adj_kernel(const float* __restrict__ E, bf16* __restrict__ Sbf) {
  int n = blockIdx.x;
  int t = threadIdx.x;
  __shared__ float En[DIMD];
  __shared__ float red[256];
  if (t < DIMD) En[t] = E[n * DIMD + t];
  __syncthreads();
  float er[16];
#pragma unroll
  for (int d = 0; d < 16; ++d) er[d] = En[d];

  float v[8];
#pragma unroll
  for (int j = 0; j < 8; ++j) {
    int col = t + j * 256;
    const float4* p = reinterpret_cast<const float4*>(E + col * DIMD);
    float4 a = p[0], b = p[1], c = p[2], d = p[3];
    float s = er[0]*a.x + er[1]*a.y + er[2]*a.z + er[3]*a.w
            + er[4]*b.x + er[5]*b.y + er[6]*b.z + er[7]*b.w
            + er[8]*c.x + er[9]*c.y + er[10]*c.z + er[11]*c.w
            + er[12]*d.x + er[13]*d.y + er[14]*d.z + er[15]*d.w;
    v[j] = fmaxf(s, 0.f);
  }
  float m = v[0];
#pragma unroll
  for (int j = 1; j < 8; ++j) m = fmaxf(m, v[j]);
  red[t] = m; __syncthreads();
  for (int s = 128; s > 0; s >>= 1) {
    if (t < s) red[t] = fmaxf(red[t], red[t + s]);
    __syncthreads();
  }
  float rowmax = red[0];
  __syncthreads();
  float e[8];
  float sum = 0.f;
#pragma unroll
  for (int j = 0; j < 8; ++j) { e[j] = __expf(v[j] - rowmax); sum += e[j]; }
  red[t] = sum; __syncthreads();
  for (int s = 128; s > 0; s >>= 1) {
    if (t < s) red[t] += red[t + s];
    __syncthreads();
  }
  float inv = 1.f / red[0];
#pragma unroll
  for (int j = 0; j < 8; ++j)
    Sbf[(size_t)n * NND + t + j * 256] = (bf16)(e[j] * inv);
}

// ---------------------------------------------------------------
// K2: pack concat(x,state) transposed: XT[(b*66+c)][m] bf16
// grid = B * (N/64), 256 thr
// ---------------------------------------------------------------
__global__ __launch_bounds__(256)
void pack_xs_kernel(const float* __restrict__ x, const float* __restrict__ state,
                    bf16* __restrict__ XT) {
  int b  = blockIdx.x >> 5;
  int n0 = (blockIdx.x & 31) * 64;
  int t  = threadIdx.x;
  __shared__ float tile[66][65];
  for (int idx = t; idx < 66 * 64; idx += 256) {
    int nn = idx / 66;
    int c  = idx - nn * 66;
    int bn = (b << 11) + n0 + nn;
    float v = (c < 2) ? x[bn * 2 + c] : state[(bn << 6) + c - 2];
    tile[c][nn] = v;
  }
  __syncthreads();
  for (int idx = t; idx < 66 * 64; idx += 256) {
    int c = idx >> 6;
    int nn = idx & 63;
    XT[(size_t)(b * 66 + c) * NND + n0 + nn] = (bf16)tile[c][nn];
  }
}

// ---------------------------------------------------------------
// K5: pack candidate (B,N,66) f32 -> transposed bf16 panel
// ---------------------------------------------------------------
__global__ __launch_bounds__(256)
void pack_c_kernel(const float* __restrict__ cf, bf16* __restrict__ XT) {
  int b  = blockIdx.x >> 5;
  int n0 = (blockIdx.x & 31) * 64;
  int t  = threadIdx.x;
  __shared__ float tile[66][65];
  for (int idx = t; idx < 66 * 64; idx += 256) {
    int nn = idx / 66;
    int c  = idx - nn * 66;
    tile[c][nn] = cf[(size_t)((b << 11) + n0 + nn) * 66 + c];
  }
  __syncthreads();
  for (int idx = t; idx < 66 * 64; idx += 256) {
    int c = idx >> 6;
    int nn = idx & 63;
    XT[(size_t)(b * 66 + c) * NND + n0 + nn] = (bf16)tile[c][nn];
  }
}

// ---------------------------------------------------------------
// K3: CT[c][n] = sum_m A[n][m] * BT[c][m]    (bf16 MFMA, f32 acc)
// A: 2048x2048 row-major. BT: NPADC x 2048 row-major. CT: NPADC x 2048.
// grid = (2048/64, NPADC/64), 256 thr (4 waves, each a 32x32 quadrant)
// ---------------------------------------------------------------
__global__ __launch_bounds__(256)
void gemm_kernel(const bf16* __restrict__ A, const bf16* __restrict__ BT,
                 float* __restrict__ CT, bf16* __restrict__ CTbf, int doBf) {
  const int K = NND;
  __shared__ bf16 As[64][72];
  __shared__ bf16 Bs[64][72];
  int t = threadIdx.x;
  int m0 = blockIdx.x * 64;   // output n range
  int c0 = blockIdx.y * 64;   // output c range
  int lane = t & 63;
  int w = t >> 6;
  int wr = w >> 1, wc = w & 1;

  int sr = t >> 3;            // 0..31
  int sc = (t & 7) << 3;      // 0..56

  f32x4 acc[2][2] = {};

  for (int k0 = 0; k0 < K; k0 += 64) {
    __syncthreads();
    *reinterpret_cast<bf16x8*>(&As[sr][sc]) =
        *reinterpret_cast<const bf16x8*>(&A[(size_t)(m0 + sr) * K + k0 + sc]);
    *reinterpret_cast<bf16x8*>(&As[sr + 32][sc]) =
        *reinterpret_cast<const bf16x8*>(&A[(size_t)(m0 + sr + 32) * K + k0 + sc]);
    *reinterpret_cast<bf16x8*>(&Bs[sr][sc]) =
        *reinterpret_cast<const bf16x8*>(&BT[(size_t)(c0 + sr) * K + k0 + sc]);
    *reinterpret_cast<bf16x8*>(&Bs[sr + 32][sc]) =
        *reinterpret_cast<const bf16x8*>(&BT[(size_t)(c0 + sr + 32) * K + k0 + sc]);
    __syncthreads();
#pragma unroll
    for (int kk = 0; kk < 64; kk += 32) {
      int row = lane & 15;
      int kc = kk + ((lane >> 4) << 3);
      bf16x8 a0 = *reinterpret_cast<const bf16x8*>(&As[wr * 32 + row][kc]);
      bf16x8 a1 = *reinterpret_cast<const bf16x8*>(&As[wr * 32 + 16 + row][kc]);
      bf16x8 b0 = *reinterpret_cast<const bf16x8*>(&Bs[wc * 32 + row][kc]);
      bf16x8 b1 = *reinterpret_cast<const bf16x8*>(&Bs[wc * 32 + 16 + row][kc]);
      acc[0][0] = __builtin_amdgcn_mfma_f32_16x16x32_bf16(a0, b0, acc[0][0], 0, 0, 0);
      acc[0][1] = __builtin_amdgcn_mfma_f32_16x16x32_bf16(a0, b1, acc[0][1], 0, 0, 0);
      acc[1][0] = __builtin_amdgcn_mfma_f32_16x16x32_bf16(a1, b0, acc[1][0], 0, 0, 0);
      acc[1][1] = __builtin_amdgcn_mfma_f32_16x16x32_bf16(a1, b1, acc[1][1], 0, 0, 0);
    }
  }

#pragma unroll
  for (int mi = 0; mi < 2; ++mi) {
#pragma unroll
    for (int ni = 0; ni < 2; ++ni) {
      int nbase = m0 + wr * 32 + mi * 16 + ((lane >> 4) << 2);
      int cidx  = c0 + wc * 32 + ni * 16 + (lane & 15);
      *reinterpret_cast<f32x4*>(&CT[(size_t)cidx * NND + nbase]) = acc[mi][ni];
      if (doBf) {
        bf16x4 pb = __builtin_convertvector(acc[mi][ni], bf16x4);
        *reinterpret_cast<bf16x4*>(&CTbf[(size_t)cidx * NND + nbase]) = pb;
      }
    }
  }
}

// ---------------------------------------------------------------
// K4: gate — per-block 8 nodes. out o<64 -> z ; o>=64 -> r -> cand
// ---------------------------------------------------------------
__global__ __launch_bounds__(256)
void gate_kernel(const float* __restrict__ x, const float* __restrict__ state,
                 const float* __restrict__ E, const float* __restrict__ Wp,
                 const float* __restrict__ Bp, const float* __restrict__ Y1T,
                 const float* __restrict__ Y2T, float* __restrict__ zout,
                 float* __restrict__ candf) {
  int n0 = blockIdx.x * 8;
  int t = threadIdx.x;
  int o = t & 127;
  int grp = t >> 7;   // nodes grp*4 .. grp*4+3
  __shared__ float xg[8][8][200];

  float Ereg[4][16];
#pragma unroll
  for (int nn = 0; nn < 4; ++nn) {
    const float* ep = E + (size_t)(n0 + grp * 4 + nn) * 16;
#pragma unroll
    for (int d = 0; d < 16; ++d) Ereg[nn][d] = ep[d];
  }

  for (int idx = t; idx < 528 * 8; idx += 256) {
    int row = idx >> 3;
    int nn = idx & 7;
    int b = row / 66;
    int i = row - b * 66;
    int node = n0 + nn;
    int bn = (b << 11) + node;
    float x0 = (i < 2) ? x[bn * 2 + i] : state[(bn << 6) + i - 2];
    float y1 = Y1T[(size_t)row * NND + node];
    float y2 = Y2T[(size_t)row * NND + node];
    xg[nn][b][i] = x0;
    xg[nn][b][66 + i] = y1;
    xg[nn][b][132 + i] = 2.f * y2 - x0;
  }
  __syncthreads();

  float acc[4][8];
#pragma unroll
  for (int nn = 0; nn < 4; ++nn) {
    float bias = 0.f;
#pragma unroll
    for (int d = 0; d < 16; ++d) bias += Ereg[nn][d] * Bp[d * 128 + o];
#pragma unroll
    for (int b = 0; b < 8; ++b) acc[nn][b] = bias;
  }

  float w0[16], w1[16], p0[16], p1[16];
#pragma unroll
  for (int d = 0; d < 16; ++d) {
    w0[d] = Wp[(size_t)(d * 198 + 0) * 128 + o];
    w1[d] = Wp[(size_t)(d * 198 + 1) * 128 + o];
  }
  for (int ki = 0; ki < 198; ki += 2) {
    if (ki + 2 < 198) {
#pragma unroll
      for (int d = 0; d < 16; ++d) {
        p0[d] = Wp[(size_t)(d * 198 + ki + 2) * 128 + o];
        p1[d] = Wp[(size_t)(d * 198 + ki + 3) * 128 + o];
      }
    }
#pragma unroll
    for (int nn = 0; nn < 4; ++nn) {
      float wn0 = 0.f, wn1 = 0.f;
#pragma unroll
      for (int d = 0; d < 16; ++d) { wn0 += Ereg[nn][d] * w0[d]; wn1 += Ereg[nn][d] * w1[d]; }
      const float* xp = &xg[grp * 4 + nn][0][ki];
#pragma unroll
      for (int b = 0; b < 8; ++b) {
        float2 g = *reinterpret_cast<const float2*>(xp + b * 200);
        acc[nn][b] += g.x * wn0 + g.y * wn1;
      }
    }
#pragma unroll
    for (int d = 0; d < 16; ++d) { w0[d] = p0[d]; w1[d] = p1[d]; }
  }

#pragma unroll
  for (int nn = 0; nn < 4; ++nn) {
    int node = n0 + grp * 4 + nn;
#pragma unroll
    for (int b = 0; b < 8; ++b) {
      float s = 1.f / (1.f + __expf(-acc[nn][b]));
      int bn = (b << 11) + node;
      if (o < 64) {
        zout[(size_t)(bn << 6) + o] = s;
      } else {
        candf[(size_t)bn * 66 + 2 + (o - 64)] = s * state[(bn << 6) + (o - 64)];
      }
      if (o < 2) candf[(size_t)bn * 66 + o] = x[bn * 2 + o];
    }
  }
}

// ---------------------------------------------------------------
// K7: update — tanh + final gate combine -> h
// ---------------------------------------------------------------
__global__ __launch_bounds__(256)
void update_kernel(const float* __restrict__ candf, const float* __restrict__ state,
                   const float* __restrict__ E, const float* __restrict__ Wp,
                   const float* __restrict__ Bp, const float* __restrict__ Z1T,
                   const float* __restrict__ Z2T, const float* __restrict__ zbuf,
                   float* __restrict__ out) {
  int n0 = blockIdx.x * 8;
  int t = threadIdx.x;
  int o = t & 63;
  int grp = t >> 6;   // nodes grp*2, grp*2+1
  __shared__ float xg[8][8][200];

  float Ereg[2][16];
#pragma unroll
  for (int nn = 0; nn < 2; ++nn) {
    const float* ep = E + (size_t)(n0 + grp * 2 + nn) * 16;
#pragma unroll
    for (int d = 0; d < 16; ++d) Ereg[nn][d] = ep[d];
  }

  for (int idx = t; idx < 528 * 8; idx += 256) {
    int row = idx >> 3;
    int nn = idx & 7;
    int b = row / 66;
    int i = row - b * 66;
    int node = n0 + nn;
    float c0 = candf[(size_t)((b << 11) + node) * 66 + i];
    float z1 = Z1T[(size_t)row * NND + node];
    float z2 = Z2T[(size_t)row * NND + node];
    xg[nn][b][i] = c0;
    xg[nn][b][66 + i] = z1;
    xg[nn][b][132 + i] = 2.f * z2 - c0;
  }
  __syncthreads();

  float acc[2][8];
#pragma unroll
  for (int nn = 0; nn < 2; ++nn) {
    float bias = 0.f;
#pragma unroll
    for (int d = 0; d < 16; ++d) bias += Ereg[nn][d] * Bp[d * 64 + o];
#pragma unroll
    for (int b = 0; b < 8; ++b) acc[nn][b] = bias;
  }

  float w0[16], w1[16], p0[16], p1[16];
#pragma unroll
  for (int d = 0; d < 16; ++d) {
    w0[d] = Wp[(size_t)(d * 198 + 0) * 64 + o];
    w1[d] = Wp[(size_t)(d * 198 + 1) * 64 + o];
  }
  for (int ki = 0; ki < 198; ki += 2) {
    if (ki + 2 < 198) {
#pragma unroll
      for (int d = 0; d < 16; ++d) {
        p0[d] = Wp[(size_t)(d * 198 + ki + 2) * 64 + o];
        p1[d] = Wp[(size_t)(d * 198 + ki + 3) * 64 + o];
      }
    }
#pragma unroll
    for (int nn = 0; nn < 2; ++nn) {
      float wn0 = 0.f, wn1 = 0.f;
#pragma unroll
      for (int d = 0; d < 16; ++d) { wn0 += Ereg[nn][d] * w0[d]; wn1 += Ereg[nn][d] * w1[d]; }
      const float* xp = &xg[grp * 2 + nn][0][ki];
#pragma unroll
      for (int b = 0; b < 8; ++b) {
        float2 g = *reinterpret_cast<const float2*>(xp + b * 200);
        acc[nn][b] += g.x * wn0 + g.y * wn1;
      }
    }
#pragma unroll
    for (int d = 0; d < 16; ++d) { w0[d] = p0[d]; w1[d] = p1[d]; }
  }

#pragma unroll
  for (int nn = 0; nn < 2; ++nn) {
    int node = n0 + grp * 2 + nn;
#pragma unroll
    for (int b = 0; b < 8; ++b) {
      int bn = (b << 11) + node;
      float hc = tanhf(acc[nn][b]);
      float zz = zbuf[(size_t)(bn << 6) + o];
      float st = state[(size_t)(bn << 6) + o];
      out[(size_t)(bn << 6) + o] = (1.f - zz) * st + zz * hc;
    }
  }
}

// ---------------------------------------------------------------
extern "C" void kernel_launch(void* const* d_in, const int* in_sizes, int n_in,
                              void* d_out, int out_size, void* d_ws, size_t ws_size,
                              hipStream_t stream) {
  const float* x     = (const float*)d_in[0];
  const float* state = (const float*)d_in[1];
  const float* E     = (const float*)d_in[2];
  const float* WpG   = (const float*)d_in[3];
  const float* BpG   = (const float*)d_in[4];
  const float* WpU   = (const float*)d_in[5];
  const float* BpU   = (const float*)d_in[6];
  float* out = (float*)d_out;

  char* ws = (char*)d_ws;
  bf16*  Sbf   = (bf16*)ws;  ws += (size_t)NND * NND * 2;            // 8 MB
  bf16*  XT    = (bf16*)ws;  ws += (size_t)NPADC * NND * 2;          // 2.25 MB (also candT)
  float* Y1T   = (float*)ws; ws += (size_t)NPADC * NND * 4;          // 4.5 MB  (also Z1T)
  bf16*  Y1Tbf = (bf16*)ws;  ws += (size_t)NPADC * NND * 2;          // 2.25 MB (also Z1Tbf)
  float* Y2T   = (float*)ws; ws += (size_t)NPADC * NND * 4;          // 4.5 MB  (also Z2T)
  float* zbuf  = (float*)ws; ws += (size_t)NBB * NND * 64 * 4;       // 4 MB
  float* candf = (float*)ws; ws += (size_t)NBB * NND * 66 * 4;       // 4.3 MB

  dim3 blk(256);
  dim3 gemmGrid(NND / 64, NPADC / 64);

  adj_kernel<<<NND, blk, 0, stream>>>(E, Sbf);
  pack_xs_kernel<<<256, blk, 0, stream>>>(x, state, XT);
  gemm_kernel<<<gemmGrid, blk, 0, stream>>>(Sbf, XT, Y1T, Y1Tbf, 1);
  gemm_kernel<<<gemmGrid, blk, 0, stream>>>(Sbf, Y1Tbf, Y2T, nullptr, 0);
  gate_kernel<<<NND / 8, blk, 0, stream>>>(x, state, E, WpG, BpG, Y1T, Y2T, zbuf, candf);
  pack_c_kernel<<<256, blk, 0, stream>>>(candf, XT);
  gemm_kernel<<<gemmGrid, blk, 0, stream>>>(Sbf, XT, Y1T, Y1Tbf, 1);
  gemm_kernel<<<gemmGrid, blk, 0, stream>>>(Sbf, Y1Tbf, Y2T, nullptr, 0);
  update_kernel<<<NND / 8, blk, 0, stream>>>(candf, state, E, WpU, BpU, Y1T, Y2T, zbuf, out);
}

// Round 2
// 222.980 us; speedup vs baseline: 1.6923x; 1.6923x over previous
//
#include <hip/hip_runtime.h>

typedef __bf16 bf16;
typedef __bf16 bf16x8 __attribute__((ext_vector_type(8)));
typedef __bf16 bf16x4 __attribute__((ext_vector_type(4)));
typedef float  f32x4  __attribute__((ext_vector_type(4)));

#define NND   2048      // nodes
#define DIMD  16        // embedding dim
#define NBB   8         // batch
#define CCC   66        // C_in + H
#define NPADC 576       // padded panel rows (>= 528, mult of 64)
#define KEXP  3200      // expanded K: 198 ki * 16 d + bias chunk, padded to 200*16

__device__ __forceinline__ float sigf(float v) { return 1.f / (1.f + __expf(-v)); }

__device__ __forceinline__ bf16x8 ld8(const bf16* p) {
  bf16x4 lo = *(const bf16x4*)p;
  bf16x4 hi = *(const bf16x4*)(p + 4);
  return __builtin_shufflevector(lo, hi, 0, 1, 2, 3, 4, 5, 6, 7);
}

// ---------------------------------------------------------------
// K1: S = softmax(relu(E E^T)) rows, bf16 out. One block per row.
// ---------------------------------------------------------------
__global__ __launch_bounds__(256)
void adj_kernel(const float* __restrict__ E, bf16* __restrict__ Sbf) {
  int n = blockIdx.x;
  int t = threadIdx.x;
  __shared__ float En[DIMD];
  __shared__ float red[256];
  if (t < DIMD) En[t] = E[n * DIMD + t];
  __syncthreads();
  float er[16];
#pragma unroll
  for (int d = 0; d < 16; ++d) er[d] = En[d];

  float v[8];
#pragma unroll
  for (int j = 0; j < 8; ++j) {
    int col = t + j * 256;
    const float4* p = reinterpret_cast<const float4*>(E + col * DIMD);
    float4 a = p[0], b = p[1], c = p[2], d = p[3];
    float s = er[0]*a.x + er[1]*a.y + er[2]*a.z + er[3]*a.w
            + er[4]*b.x + er[5]*b.y + er[6]*b.z + er[7]*b.w
            + er[8]*c.x + er[9]*c.y + er[10]*c.z + er[11]*c.w
            + er[12]*d.x + er[13]*d.y + er[14]*d.z + er[15]*d.w;
    v[j] = fmaxf(s, 0.f);
  }
  float m = v[0];
#pragma unroll
  for (int j = 1; j < 8; ++j) m = fmaxf(m, v[j]);
  red[t] = m; __syncthreads();
  for (int s = 128; s > 0; s >>= 1) {
    if (t < s) red[t] = fmaxf(red[t], red[t + s]);
    __syncthreads();
  }
  float rowmax = red[0];
  __syncthreads();
  float e[8];
  float sum = 0.f;
#pragma unroll
  for (int j = 0; j < 8; ++j) { e[j] = __expf(v[j] - rowmax); sum += e[j]; }
  red[t] = sum; __syncthreads();
  for (int s = 128; s > 0; s >>= 1) {
    if (t < s) red[t] += red[t + s];
    __syncthreads();
  }
  float inv = 1.f / red[0];
#pragma unroll
  for (int j = 0; j < 8; ++j)
    Sbf[(size_t)n * NND + t + j * 256] = (bf16)(e[j] * inv);
}

// ---------------------------------------------------------------
// K2: pack concat(x,state) transposed: XT[(b*66+c)][n] bf16.
// Also writes the x-rows (c<2) of candT (cand shares them).
// grid = B * (N/64), 256 thr
// ---------------------------------------------------------------
__global__ __launch_bounds__(256)
void pack_xs_kernel(const float* __restrict__ x, const float* __restrict__ state,
                    bf16* __restrict__ XT, bf16* __restrict__ candT) {
  int b  = blockIdx.x >> 5;
  int n0 = (blockIdx.x & 31) * 64;
  int t  = threadIdx.x;
  __shared__ float tile[66][65];
  for (int idx = t; idx < 66 * 64; idx += 256) {
    int nn = idx / 66;
    int c  = idx - nn * 66;
    int bn = (b << 11) + n0 + nn;
    float v = (c < 2) ? x[bn * 2 + c] : state[(bn << 6) + c - 2];
    tile[c][nn] = v;
  }
  __syncthreads();
  for (int idx = t; idx < 66 * 64; idx += 256) {
    int c = idx >> 6;
    int nn = idx & 63;
    bf16 v = (bf16)tile[c][nn];
    size_t off = (size_t)(b * 66 + c) * NND + n0 + nn;
    XT[off] = v;
    if (c < 2) candT[off] = v;
  }
}

// ---------------------------------------------------------------
// K3: graph GEMM  CT[c][n] = sum_m A[n][m] * BT[c][m]  -> bf16 out
// grid = (2048/64, NPADC/64), 256 thr (4 waves, 32x32 quadrants)
// ---------------------------------------------------------------
__global__ __launch_bounds__(256)
void gemm_kernel(const bf16* __restrict__ A, const bf16* __restrict__ BT,
                 bf16* __restrict__ CTbf) {
  const int K = NND;
  __shared__ bf16 As[64][72];
  __shared__ bf16 Bs[64][72];
  int t = threadIdx.x;
  int m0 = blockIdx.x * 64;   // output n range
  int c0 = blockIdx.y * 64;   // output c range
  int lane = t & 63;
  int w = t >> 6;
  int wr = w >> 1, wc = w & 1;

  int sr = t >> 3;            // 0..31
  int sc = (t & 7) << 3;      // 0..56

  f32x4 acc[2][2] = {};

  for (int k0 = 0; k0 < K; k0 += 64) {
    // reg-stage the global loads before the barrier (hide latency under MFMA)
    bf16x8 a0r = *reinterpret_cast<const bf16x8*>(&A[(size_t)(m0 + sr) * K + k0 + sc]);
    bf16x8 a1r = *reinterpret_cast<const bf16x8*>(&A[(size_t)(m0 + sr + 32) * K + k0 + sc]);
    bf16x8 b0r = *reinterpret_cast<const bf16x8*>(&BT[(size_t)(c0 + sr) * K + k0 + sc]);
    bf16x8 b1r = *reinterpret_cast<const bf16x8*>(&BT[(size_t)(c0 + sr + 32) * K + k0 + sc]);
    __syncthreads();
    *reinterpret_cast<bf16x8*>(&As[sr][sc])      = a0r;
    *reinterpret_cast<bf16x8*>(&As[sr + 32][sc]) = a1r;
    *reinterpret_cast<bf16x8*>(&Bs[sr][sc])      = b0r;
    *reinterpret_cast<bf16x8*>(&Bs[sr + 32][sc]) = b1r;
    __syncthreads();
#pragma unroll
    for (int kk = 0; kk < 64; kk += 32) {
      int row = lane & 15;
      int kc = kk + ((lane >> 4) << 3);
      bf16x8 a0 = *reinterpret_cast<const bf16x8*>(&As[wr * 32 + row][kc]);
      bf16x8 a1 = *reinterpret_cast<const bf16x8*>(&As[wr * 32 + 16 + row][kc]);
      bf16x8 b0 = *reinterpret_cast<const bf16x8*>(&Bs[wc * 32 + row][kc]);
      bf16x8 b1 = *reinterpret_cast<const bf16x8*>(&Bs[wc * 32 + 16 + row][kc]);
      acc[0][0] = __builtin_amdgcn_mfma_f32_16x16x32_bf16(a0, b0, acc[0][0], 0, 0, 0);
      acc[0][1] = __builtin_amdgcn_mfma_f32_16x16x32_bf16(a0, b1, acc[0][1], 0, 0, 0);
      acc[1][0] = __builtin_amdgcn_mfma_f32_16x16x32_bf16(a1, b0, acc[1][0], 0, 0, 0);
      acc[1][1] = __builtin_amdgcn_mfma_f32_16x16x32_bf16(a1, b1, acc[1][1], 0, 0, 0);
    }
  }

#pragma unroll
  for (int mi = 0; mi < 2; ++mi) {
#pragma unroll
    for (int ni = 0; ni < 2; ++ni) {
      int nbase = m0 + wr * 32 + mi * 16 + ((lane >> 4) << 2);
      int cidx  = c0 + wc * 32 + ni * 16 + (lane & 15);
      bf16x4 pb = __builtin_convertvector(acc[mi][ni], bf16x4);
      *reinterpret_cast<bf16x4*>(&CTbf[(size_t)cidx * NND + nbase]) = pb;
    }
  }
}

// ---------------------------------------------------------------
// K4: prep  B'T[o][ki*16+d] = Wp[d][ki/66][ki%66][o]  (bf16),
//     row ki==198 -> bias Bp[d][o], ki==199 -> 0.
// grid = (KEXP/64, ncols/64)
// ---------------------------------------------------------------
__global__ __launch_bounds__(256)
void prep_w_kernel(const float* __restrict__ Wp, const float* __restrict__ Bp,
                   bf16* __restrict__ BT, int ncols) {
  __shared__ float tile[64][65];
  int k0 = blockIdx.x * 64;
  int o0 = blockIdx.y * 64;
  int t = threadIdx.x;
  for (int idx = t; idx < 4096; idx += 256) {
    int kr = idx >> 6, oc = idx & 63;
    int kp = k0 + kr;
    int ki = kp >> 4, d = kp & 15;
    float v;
    if (ki < 198) {
      int kc3 = ki / 66;
      int i = ki - kc3 * 66;
      v = Wp[(size_t)((d * 3 + kc3) * 66 + i) * ncols + o0 + oc];
    } else if (ki == 198) {
      v = Bp[d * ncols + o0 + oc];
    } else {
      v = 0.f;
    }
    tile[kr][oc] = v;
  }
  __syncthreads();
  for (int idx = t; idx < 4096; idx += 256) {
    int orow = idx >> 6, kc = idx & 63;
    BT[(size_t)(o0 + orow) * KEXP + k0 + kc] = (bf16)tile[kc][orow];
  }
}

// ---------------------------------------------------------------
// K5: expansion GEMM  out[bn][o] = sum_k A'[bn][k] * B'[k][o]
//   A'[bn][ki*16+d] = xg(bn,ki) * E[n][d]  (built on the fly in LDS)
//   xg: ki<66 -> XT, <132 -> Y1, <198 -> 2*Y2 - XT, ==198 -> 1 (bias), ==199 -> 0
// mode 0 (gate, ncols=128): o<64 -> zT[o][bn]=sigmoid; o>=64 -> candT r*state
// mode 1 (update, ncols=64): out = (1-z)*state + z*tanh(acc)
// grid = (16384/64, ncols/64), 256 thr
// ---------------------------------------------------------------
__global__ __launch_bounds__(256)
void wgemm_kernel(const bf16* __restrict__ XTsrc, const bf16* __restrict__ Y1src,
                  const bf16* __restrict__ Y2src, const float* __restrict__ E,
                  const bf16* __restrict__ BT, int mode,
                  const float* __restrict__ state, float* __restrict__ zT,
                  bf16* __restrict__ candT, float* __restrict__ out) {
  __shared__ bf16 As[64][68];
  __shared__ bf16 Bs[64][72];
  int t = threadIdx.x;
  int m0 = blockIdx.x * 64;   // bn tile
  int c0 = blockIdx.y * 64;   // o tile

  // A-staging ids (thread = kk*64 + r)
  int kk = t >> 6;            // 0..3 : ki sub-index (wave-uniform)
  int r  = t & 63;            // row within tile
  int bn = m0 + r;
  int b  = bn >> 11;
  int n  = bn & 2047;
  const float4* ep = reinterpret_cast<const float4*>(E + n * 16);
  float4 e0 = ep[0], e1 = ep[1], e2 = ep[2], e3 = ep[3];

  // B-staging ids
  int sr = t >> 3;            // 0..31
  int sc = (t & 7) << 3;      // 0..56

  // mfma ids
  int lane = t & 63;
  int w = t >> 6;
  int wr = w >> 1, wc = w & 1;
  int row16 = lane & 15;
  int kq = (lane >> 4) << 3;

  f32x4 acc[2][2] = {};

  for (int k0 = 0; k0 < KEXP; k0 += 64) {
    // ---- global reads (before barrier, overlap with prev MFMA) ----
    int ki = (k0 >> 4) + kk;
    float val;
    if (ki < 132) {
      const bf16* src = (ki < 66) ? (XTsrc + (size_t)(b * 66 + ki) * NND)
                                  : (Y1src + (size_t)(b * 66 + ki - 66) * NND);
      val = (float)src[n];
    } else if (ki < 198) {
      size_t off = (size_t)(b * 66 + ki - 132) * NND + n;
      val = 2.f * (float)Y2src[off] - (float)XTsrc[off];
    } else {
      val = (ki == 198) ? 1.f : 0.f;
    }
    bf16x8 b0r = *reinterpret_cast<const bf16x8*>(&BT[(size_t)(c0 + sr) * KEXP + k0 + sc]);
    bf16x8 b1r = *reinterpret_cast<const bf16x8*>(&BT[(size_t)(c0 + sr + 32) * KEXP + k0 + sc]);

    __syncthreads();
    // ---- expansion write: As[r][kk*16 + d] = val * E[n][d] ----
    f32x4 p0 = { val * e0.x, val * e0.y, val * e0.z, val * e0.w };
    f32x4 p1 = { val * e1.x, val * e1.y, val * e1.z, val * e1.w };
    f32x4 p2 = { val * e2.x, val * e2.y, val * e2.z, val * e2.w };
    f32x4 p3 = { val * e3.x, val * e3.y, val * e3.z, val * e3.w };
    *reinterpret_cast<bf16x4*>(&As[r][kk * 16 + 0])  = __builtin_convertvector(p0, bf16x4);
    *reinterpret_cast<bf16x4*>(&As[r][kk * 16 + 4])  = __builtin_convertvector(p1, bf16x4);
    *reinterpret_cast<bf16x4*>(&As[r][kk * 16 + 8])  = __builtin_convertvector(p2, bf16x4);
    *reinterpret_cast<bf16x4*>(&As[r][kk * 16 + 12]) = __builtin_convertvector(p3, bf16x4);
    *reinterpret_cast<bf16x8*>(&Bs[sr][sc])      = b0r;
    *reinterpret_cast<bf16x8*>(&Bs[sr + 32][sc]) = b1r;
    __syncthreads();

#pragma unroll
    for (int kk2 = 0; kk2 < 64; kk2 += 32) {
      int kc = kk2 + kq;
      bf16x8 a0 = ld8(&As[wr * 32 + row16][kc]);
      bf16x8 a1 = ld8(&As[wr * 32 + 16 + row16][kc]);
      bf16x8 b0 = *reinterpret_cast<const bf16x8*>(&Bs[wc * 32 + row16][kc]);
      bf16x8 b1 = *reinterpret_cast<const bf16x8*>(&Bs[wc * 32 + 16 + row16][kc]);
      acc[0][0] = __builtin_amdgcn_mfma_f32_16x16x32_bf16(a0, b0, acc[0][0], 0, 0, 0);
      acc[0][1] = __builtin_amdgcn_mfma_f32_16x16x32_bf16(a0, b1, acc[0][1], 0, 0, 0);
      acc[1][0] = __builtin_amdgcn_mfma_f32_16x16x32_bf16(a1, b0, acc[1][0], 0, 0, 0);
      acc[1][1] = __builtin_amdgcn_mfma_f32_16x16x32_bf16(a1, b1, acc[1][1], 0, 0, 0);
    }
  }

#pragma unroll
  for (int mi = 0; mi < 2; ++mi) {
#pragma unroll
    for (int ni = 0; ni < 2; ++ni) {
      int nb = m0 + wr * 32 + mi * 16 + ((lane >> 4) << 2);  // 4 consecutive bn
      int oc = c0 + wc * 32 + ni * 16 + (lane & 15);
      f32x4 a = acc[mi][ni];
      if (mode == 0) {
        if (oc < 64) {
          f32x4 zv = { sigf(a.x), sigf(a.y), sigf(a.z), sigf(a.w) };
          *reinterpret_cast<f32x4*>(&zT[(size_t)oc * 16384 + nb]) = zv;
        } else {
          int h = oc - 64;
          int bb = nb >> 11, nn = nb & 2047;
          bf16x4 cv;
#pragma unroll
          for (int j = 0; j < 4; ++j) {
            float st = state[(size_t)(nb + j) * 64 + h];
            cv[j] = (bf16)(sigf(a[j]) * st);
          }
          *reinterpret_cast<bf16x4*>(&candT[(size_t)(bb * 66 + 2 + h) * NND + nn]) = cv;
        }
      } else {
        f32x4 zv = *reinterpret_cast<const f32x4*>(&zT[(size_t)oc * 16384 + nb]);
#pragma unroll
        for (int j = 0; j < 4; ++j) {
          float st = state[(size_t)(nb + j) * 64 + oc];
          float hc = tanhf(a[j]);
          out[(size_t)(nb + j) * 64 + oc] = (1.f - zv[j]) * st + zv[j] * hc;
        }
      }
    }
  }
}

// ---------------------------------------------------------------
extern "C" void kernel_launch(void* const* d_in, const int* in_sizes, int n_in,
                              void* d_out, int out_size, void* d_ws, size_t ws_size,
                              hipStream_t stream) {
  const float* x     = (const float*)d_in[0];
  const float* state = (const float*)d_in[1];
  const float* E     = (const float*)d_in[2];
  const float* WpG   = (const float*)d_in[3];
  const float* BpG   = (const float*)d_in[4];
  const float* WpU   = (const float*)d_in[5];
  const float* BpU   = (const float*)d_in[6];
  float* out = (float*)d_out;

  char* ws = (char*)d_ws;
  bf16*  Sbf   = (bf16*)ws;  ws += (size_t)NND * NND * 2;        // 8 MB
  bf16*  XT    = (bf16*)ws;  ws += (size_t)NPADC * NND * 2;      // 2.25 MB
  bf16*  candT = (bf16*)ws;  ws += (size_t)NPADC * NND * 2;      // 2.25 MB
  bf16*  Y1    = (bf16*)ws;  ws += (size_t)NPADC * NND * 2;      // 2.25 MB (also Z1)
  bf16*  Y2    = (bf16*)ws;  ws += (size_t)NPADC * NND * 2;      // 2.25 MB (also Z2)
  float* zT    = (float*)ws; ws += (size_t)64 * NBB * NND * 4;   // 4 MB
  bf16*  BTg   = (bf16*)ws;  ws += (size_t)128 * KEXP * 2;       // 800 KB
  bf16*  BTu   = (bf16*)ws;  ws += (size_t)64 * KEXP * 2;        // 400 KB

  dim3 blk(256);
  dim3 gemmGrid(NND / 64, NPADC / 64);

  prep_w_kernel<<<dim3(KEXP / 64, 2), blk, 0, stream>>>(WpG, BpG, BTg, 128);
  prep_w_kernel<<<dim3(KEXP / 64, 1), blk, 0, stream>>>(WpU, BpU, BTu, 64);
  adj_kernel<<<NND, blk, 0, stream>>>(E, Sbf);
  pack_xs_kernel<<<256, blk, 0, stream>>>(x, state, XT, candT);
  gemm_kernel<<<gemmGrid, blk, 0, stream>>>(Sbf, XT, Y1);
  gemm_kernel<<<gemmGrid, blk, 0, stream>>>(Sbf, Y1, Y2);
  wgemm_kernel<<<dim3(NBB * NND / 64, 2), blk, 0, stream>>>(XT, Y1, Y2, E, BTg, 0,
                                                            state, zT, candT, nullptr);
  gemm_kernel<<<gemmGrid, blk, 0, stream>>>(Sbf, candT, Y1);
  gemm_kernel<<<gemmGrid, blk, 0, stream>>>(Sbf, Y1, Y2);
  wgemm_kernel<<<dim3(NBB * NND / 64, 1), blk, 0, stream>>>(candT, Y1, Y2, E, BTu, 1,
                                                            state, zT, nullptr, out);
}

// Round 3
// 191.703 us; speedup vs baseline: 1.9684x; 1.1632x over previous
//
#include <hip/hip_runtime.h>

typedef __bf16 bf16;
typedef __bf16 bf16x8 __attribute__((ext_vector_type(8)));
typedef __bf16 bf16x4 __attribute__((ext_vector_type(4)));
typedef float  f32x4  __attribute__((ext_vector_type(4)));

#define NND   2048      // nodes
#define DIMD  16        // embedding dim
#define NBB   8         // batch
#define NPADC 576       // padded panel rows (>= 528, mult of 64)
#define KEXP  3328      // expanded K: 208 ki-chunks * 16 d (198 real + bias + zeros)
#define MTOT  16384     // B*N

__device__ __forceinline__ float sigf(float v) { return 1.f / (1.f + __expf(-v)); }

// ---------------------------------------------------------------
// K1: S = softmax(relu(E E^T)) rows, bf16 out. One block per row.
// ---------------------------------------------------------------
__global__ __launch_bounds__(256)
void adj_kernel(const float* __restrict__ E, bf16* __restrict__ Sbf) {
  int n = blockIdx.x;
  int t = threadIdx.x;
  __shared__ float En[DIMD];
  __shared__ float red[256];
  if (t < DIMD) En[t] = E[n * DIMD + t];
  __syncthreads();
  float er[16];
#pragma unroll
  for (int d = 0; d < 16; ++d) er[d] = En[d];

  float v[8];
#pragma unroll
  for (int j = 0; j < 8; ++j) {
    int col = t + j * 256;
    const float4* p = reinterpret_cast<const float4*>(E + col * DIMD);
    float4 a = p[0], b = p[1], c = p[2], d = p[3];
    float s = er[0]*a.x + er[1]*a.y + er[2]*a.z + er[3]*a.w
            + er[4]*b.x + er[5]*b.y + er[6]*b.z + er[7]*b.w
            + er[8]*c.x + er[9]*c.y + er[10]*c.z + er[11]*c.w
            + er[12]*d.x + er[13]*d.y + er[14]*d.z + er[15]*d.w;
    v[j] = fmaxf(s, 0.f);
  }
  float m = v[0];
#pragma unroll
  for (int j = 1; j < 8; ++j) m = fmaxf(m, v[j]);
  red[t] = m; __syncthreads();
  for (int s = 128; s > 0; s >>= 1) {
    if (t < s) red[t] = fmaxf(red[t], red[t + s]);
    __syncthreads();
  }
  float rowmax = red[0];
  __syncthreads();
  float e[8];
  float sum = 0.f;
#pragma unroll
  for (int j = 0; j < 8; ++j) { e[j] = __expf(v[j] - rowmax); sum += e[j]; }
  red[t] = sum; __syncthreads();
  for (int s = 128; s > 0; s >>= 1) {
    if (t < s) red[t] += red[t + s];
    __syncthreads();
  }
  float inv = 1.f / red[0];
#pragma unroll
  for (int j = 0; j < 8; ++j)
    Sbf[(size_t)n * NND + t + j * 256] = (bf16)(e[j] * inv);
}

// ---------------------------------------------------------------
// K2: pack concat(x,state) transposed: XT[(b*66+c)][n] bf16.
// Also writes the x-rows (c<2) of candT.
// ---------------------------------------------------------------
__global__ __launch_bounds__(256)
void pack_xs_kernel(const float* __restrict__ x, const float* __restrict__ state,
                    bf16* __restrict__ XT, bf16* __restrict__ candT) {
  int b  = blockIdx.x >> 5;
  int n0 = (blockIdx.x & 31) * 64;
  int t  = threadIdx.x;
  __shared__ float tile[66][65];
  for (int idx = t; idx < 66 * 64; idx += 256) {
    int nn = idx / 66;
    int c  = idx - nn * 66;
    int bn = (b << 11) + n0 + nn;
    float v = (c < 2) ? x[bn * 2 + c] : state[(bn << 6) + c - 2];
    tile[c][nn] = v;
  }
  __syncthreads();
  for (int idx = t; idx < 66 * 64; idx += 256) {
    int c = idx >> 6;
    int nn = idx & 63;
    bf16 v = (bf16)tile[c][nn];
    size_t off = (size_t)(b * 66 + c) * NND + n0 + nn;
    XT[off] = v;
    if (c < 2) candT[off] = v;
  }
}

// ---------------------------------------------------------------
// K3: graph GEMM partials. P[z][c][n] = sum_{k in z-half} A[n][k]*BT[c][k]
// 512 thr = 8 waves = 2 K-groups x 4 quadrant waves; K_STEP=128.
// grid = (2048/64, NPADC/64, 2)
// ---------------------------------------------------------------
__global__ __launch_bounds__(512, 6)
void gemm_kernel(const bf16* __restrict__ A, const bf16* __restrict__ BT,
                 float* __restrict__ P) {
  __shared__ bf16 As[64][136];
  __shared__ bf16 Bs[64][136];
  int t = threadIdx.x;
  int m0 = blockIdx.x * 64;
  int c0 = blockIdx.y * 64;
  int z  = blockIdx.z;
  int lane = t & 63;
  int w = t >> 6;
  int kg = w >> 2, quad = w & 3;
  int wr = quad >> 1, wc = quad & 1;
  int srow = t >> 3;          // 0..63
  int scol = (t & 7) << 3;    // 0..56
  int row16 = lane & 15;
  int kq = (lane >> 4) << 3;

  f32x4 acc[2][2] = {};
  int kbase = z * 1024;

  for (int s = 0; s < 8; ++s) {
    int k0 = kbase + s * 128;
    bf16x8 a0r = *(const bf16x8*)&A[(size_t)(m0 + srow) * NND + k0 + scol];
    bf16x8 a1r = *(const bf16x8*)&A[(size_t)(m0 + srow) * NND + k0 + 64 + scol];
    bf16x8 b0r = *(const bf16x8*)&BT[(size_t)(c0 + srow) * NND + k0 + scol];
    bf16x8 b1r = *(const bf16x8*)&BT[(size_t)(c0 + srow) * NND + k0 + 64 + scol];
    __syncthreads();
    *(bf16x8*)&As[srow][scol]      = a0r;
    *(bf16x8*)&As[srow][64 + scol] = a1r;
    *(bf16x8*)&Bs[srow][scol]      = b0r;
    *(bf16x8*)&Bs[srow][64 + scol] = b1r;
    __syncthreads();
#pragma unroll
    for (int kk2 = 0; kk2 < 64; kk2 += 32) {
      int kc = kg * 64 + kk2 + kq;
      bf16x8 a0 = *(const bf16x8*)&As[wr*32 + row16][kc];
      bf16x8 a1 = *(const bf16x8*)&As[wr*32 + 16 + row16][kc];
      bf16x8 bb0 = *(const bf16x8*)&Bs[wc*32 + row16][kc];
      bf16x8 bb1 = *(const bf16x8*)&Bs[wc*32 + 16 + row16][kc];
      acc[0][0] = __builtin_amdgcn_mfma_f32_16x16x32_bf16(a0, bb0, acc[0][0], 0,0,0);
      acc[0][1] = __builtin_amdgcn_mfma_f32_16x16x32_bf16(a0, bb1, acc[0][1], 0,0,0);
      acc[1][0] = __builtin_amdgcn_mfma_f32_16x16x32_bf16(a1, bb0, acc[1][0], 0,0,0);
      acc[1][1] = __builtin_amdgcn_mfma_f32_16x16x32_bf16(a1, bb1, acc[1][1], 0,0,0);
    }
  }

  __syncthreads();
  float* red = (float*)&As[0][0];
  if (kg == 1) {
#pragma unroll
    for (int mi = 0; mi < 2; ++mi)
#pragma unroll
      for (int ni = 0; ni < 2; ++ni)
        *(f32x4*)&red[(((quad*2 + mi)*2 + ni)*64 + lane)*4] = acc[mi][ni];
  }
  __syncthreads();
  if (kg == 0) {
#pragma unroll
    for (int mi = 0; mi < 2; ++mi)
#pragma unroll
      for (int ni = 0; ni < 2; ++ni) {
        f32x4 v = acc[mi][ni] + *(const f32x4*)&red[(((quad*2 + mi)*2 + ni)*64 + lane)*4];
        int nb = m0 + wr*32 + mi*16 + ((lane >> 4) << 2);
        int oc = c0 + wc*32 + ni*16 + (lane & 15);
        *(f32x4*)&P[((size_t)z * NPADC + oc) * NND + nb] = v;
      }
  }
}

// ---------------------------------------------------------------
// K3b: reduce partials -> bf16.  Y[i] = bf16(P0[i] + P1[i])
// grid = NPADC*NND/1024 = 1152
// ---------------------------------------------------------------
__global__ __launch_bounds__(256)
void reduce_kernel(const float* __restrict__ P, bf16* __restrict__ Y) {
  size_t i = ((size_t)blockIdx.x * 256 + threadIdx.x) * 4;
  f32x4 a = *(const f32x4*)&P[i];
  f32x4 b = *(const f32x4*)&P[(size_t)NPADC * NND + i];
  f32x4 s = a + b;
  *(bf16x4*)&Y[i] = __builtin_convertvector(s, bf16x4);
}

// ---------------------------------------------------------------
// K4: prep  B'T[o][ki*16+d] = Wp[d][ki/66][ki%66][o]  (bf16),
//     ki==198 -> bias Bp[d][o], ki>198 -> 0.   grid = (KEXP/64, ncols/64)
// ---------------------------------------------------------------
__global__ __launch_bounds__(256)
void prep_w_kernel(const float* __restrict__ Wp, const float* __restrict__ Bp,
                   bf16* __restrict__ BT, int ncols) {
  __shared__ float tile[64][65];
  int k0 = blockIdx.x * 64;
  int o0 = blockIdx.y * 64;
  int t = threadIdx.x;
  for (int idx = t; idx < 4096; idx += 256) {
    int kr = idx >> 6, oc = idx & 63;
    int kp = k0 + kr;
    int ki = kp >> 4, d = kp & 15;
    float v;
    if (ki < 198) {
      int kc3 = ki / 66;
      int i = ki - kc3 * 66;
      v = Wp[(size_t)((d * 3 + kc3) * 66 + i) * ncols + o0 + oc];
    } else if (ki == 198) {
      v = Bp[d * ncols + o0 + oc];
    } else {
      v = 0.f;
    }
    tile[kr][oc] = v;
  }
  __syncthreads();
  for (int idx = t; idx < 4096; idx += 256) {
    int orow = idx >> 6, kc = idx & 63;
    BT[(size_t)(o0 + orow) * KEXP + k0 + kc] = (bf16)tile[kc][orow];
  }
}

// ---------------------------------------------------------------
// K5: expansion GEMM partials. P[z][oc][bn] over K-half z.
// A'[bn][ki*16+d] = xg(bn,ki)*E[n][d] built in LDS.
// 512 thr, 8 waves (2 K-groups x 4 quads). grid = (MTOT/64, ncols/64, 2)
// ---------------------------------------------------------------
__global__ __launch_bounds__(512, 6)
void wgemm_kernel(const bf16* __restrict__ XTsrc, const bf16* __restrict__ Y1src,
                  const bf16* __restrict__ Y2src, const float* __restrict__ E,
                  const bf16* __restrict__ BT, int ncols, float* __restrict__ P) {
  __shared__ bf16 As[64][136];
  __shared__ bf16 Bs[64][136];
  int t = threadIdx.x;
  int m0 = blockIdx.x * 64;
  int c0 = blockIdx.y * 64;
  int z  = blockIdx.z;
  int r  = t & 63;
  int kk = t >> 6;            // 0..7 (wave-uniform)
  int bn = m0 + r;
  int b  = bn >> 11, n = bn & 2047;
  const float4* ep = (const float4*)(E + n * 16);
  float4 e0 = ep[0], e1 = ep[1], e2 = ep[2], e3 = ep[3];
  int srow = t >> 3;          // 0..63
  int scol = (t & 7) << 3;
  int lane = t & 63;
  int w = t >> 6;
  int kg = w >> 2, quad = w & 3;
  int wr = quad >> 1, wc = quad & 1;
  int row16 = lane & 15;
  int kq = (lane >> 4) << 3;

  f32x4 acc[2][2] = {};
  int kbase = z * (KEXP / 2);

  for (int s = 0; s < 13; ++s) {
    int k0 = kbase + s * 128;
    int ki = (k0 >> 4) + kk;
    float xv;
    if (ki < 66) {
      xv = (float)XTsrc[(size_t)(b * 66 + ki) * NND + n];
    } else if (ki < 132) {
      xv = (float)Y1src[(size_t)(b * 66 + ki - 66) * NND + n];
    } else if (ki < 198) {
      size_t off = (size_t)(b * 66 + ki - 132) * NND + n;
      xv = 2.f * (float)Y2src[off] - (float)XTsrc[off];
    } else {
      xv = (ki == 198) ? 1.f : 0.f;
    }
    bf16x8 b0r = *(const bf16x8*)&BT[(size_t)(c0 + srow) * KEXP + k0 + scol];
    bf16x8 b1r = *(const bf16x8*)&BT[(size_t)(c0 + srow) * KEXP + k0 + 64 + scol];
    __syncthreads();
    f32x4 q0 = { xv*e0.x, xv*e0.y, xv*e0.z, xv*e0.w };
    f32x4 q1 = { xv*e1.x, xv*e1.y, xv*e1.z, xv*e1.w };
    f32x4 q2 = { xv*e2.x, xv*e2.y, xv*e2.z, xv*e2.w };
    f32x4 q3 = { xv*e3.x, xv*e3.y, xv*e3.z, xv*e3.w };
    *(bf16x4*)&As[r][kk*16 + 0]  = __builtin_convertvector(q0, bf16x4);
    *(bf16x4*)&As[r][kk*16 + 4]  = __builtin_convertvector(q1, bf16x4);
    *(bf16x4*)&As[r][kk*16 + 8]  = __builtin_convertvector(q2, bf16x4);
    *(bf16x4*)&As[r][kk*16 + 12] = __builtin_convertvector(q3, bf16x4);
    *(bf16x8*)&Bs[srow][scol]      = b0r;
    *(bf16x8*)&Bs[srow][64 + scol] = b1r;
    __syncthreads();
#pragma unroll
    for (int kk2 = 0; kk2 < 64; kk2 += 32) {
      int kc = kg * 64 + kk2 + kq;
      bf16x8 a0 = *(const bf16x8*)&As[wr*32 + row16][kc];
      bf16x8 a1 = *(const bf16x8*)&As[wr*32 + 16 + row16][kc];
      bf16x8 bb0 = *(const bf16x8*)&Bs[wc*32 + row16][kc];
      bf16x8 bb1 = *(const bf16x8*)&Bs[wc*32 + 16 + row16][kc];
      acc[0][0] = __builtin_amdgcn_mfma_f32_16x16x32_bf16(a0, bb0, acc[0][0], 0,0,0);
      acc[0][1] = __builtin_amdgcn_mfma_f32_16x16x32_bf16(a0, bb1, acc[0][1], 0,0,0);
      acc[1][0] = __builtin_amdgcn_mfma_f32_16x16x32_bf16(a1, bb0, acc[1][0], 0,0,0);
      acc[1][1] = __builtin_amdgcn_mfma_f32_16x16x32_bf16(a1, bb1, acc[1][1], 0,0,0);
    }
  }

  __syncthreads();
  float* red = (float*)&As[0][0];
  if (kg == 1) {
#pragma unroll
    for (int mi = 0; mi < 2; ++mi)
#pragma unroll
      for (int ni = 0; ni < 2; ++ni)
        *(f32x4*)&red[(((quad*2 + mi)*2 + ni)*64 + lane)*4] = acc[mi][ni];
  }
  __syncthreads();
  if (kg == 0) {
#pragma unroll
    for (int mi = 0; mi < 2; ++mi)
#pragma unroll
      for (int ni = 0; ni < 2; ++ni) {
        f32x4 v = acc[mi][ni] + *(const f32x4*)&red[(((quad*2 + mi)*2 + ni)*64 + lane)*4];
        int nb = m0 + wr*32 + mi*16 + ((lane >> 4) << 2);
        int oc = c0 + wc*32 + ni*16 + (lane & 15);
        *(f32x4*)&P[((size_t)z * ncols + oc) * MTOT + nb] = v;
      }
  }
}

// ---------------------------------------------------------------
// K6: gate epilogue. zT[h][bn] = sig(P0z+P1z); candT[.][n] = sig(P0r+P1r)*state
// grid = MTOT/64
// ---------------------------------------------------------------
__global__ __launch_bounds__(256)
void gate_epi(const float* __restrict__ P, const float* __restrict__ state,
              float* __restrict__ zT, bf16* __restrict__ candT) {
  __shared__ float st[64][65];
  int bn0 = blockIdx.x * 64;
  int t = threadIdx.x;
#pragma unroll
  for (int i = 0; i < 16; ++i) {
    int e = i * 256 + t;
    int bnr = e >> 6, hc = e & 63;
    st[hc][bnr] = state[(size_t)(bn0 + bnr) * 64 + hc];
  }
  __syncthreads();
#pragma unroll
  for (int i = 0; i < 4; ++i) {
    int pr = i * 256 + t;
    int h = pr >> 4, bl = (pr & 15) * 4;
    int bn = bn0 + bl;
    f32x4 p0z = *(const f32x4*)&P[(size_t)h * MTOT + bn];
    f32x4 p1z = *(const f32x4*)&P[(size_t)(128 + h) * MTOT + bn];
    f32x4 p0r = *(const f32x4*)&P[(size_t)(64 + h) * MTOT + bn];
    f32x4 p1r = *(const f32x4*)&P[(size_t)(192 + h) * MTOT + bn];
    f32x4 zv; bf16x4 cv;
#pragma unroll
    for (int j = 0; j < 4; ++j) {
      zv[j] = sigf(p0z[j] + p1z[j]);
      float rv = sigf(p0r[j] + p1r[j]) * st[h][bl + j];
      cv[j] = (bf16)rv;
    }
    *(f32x4*)&zT[(size_t)h * MTOT + bn] = zv;
    int b = bn >> 11, n = bn & 2047;
    *(bf16x4*)&candT[(size_t)(b * 66 + 2 + h) * NND + n] = cv;
  }
}

// ---------------------------------------------------------------
// K7: update epilogue. out[bn][o] = (1-z)*state + z*tanh(P0+P1)
// grid = MTOT/64
// ---------------------------------------------------------------
__global__ __launch_bounds__(256)
void update_epi(const float* __restrict__ P, const float* __restrict__ state,
                const float* __restrict__ zT, float* __restrict__ out) {
  __shared__ float st[64][65];
  int bn0 = blockIdx.x * 64;
  int t = threadIdx.x;
#pragma unroll
  for (int i = 0; i < 16; ++i) {
    int e = i * 256 + t;
    int bnr = e >> 6, oc = e & 63;
    st[oc][bnr] = state[(size_t)(bn0 + bnr) * 64 + oc];
  }
  __syncthreads();
#pragma unroll
  for (int i = 0; i < 4; ++i) {
    int pr = i * 256 + t;
    int o = pr >> 4, bl = (pr & 15) * 4;
    int bn = bn0 + bl;
    f32x4 p0 = *(const f32x4*)&P[(size_t)o * MTOT + bn];
    f32x4 p1 = *(const f32x4*)&P[(size_t)(64 + o) * MTOT + bn];
    f32x4 zv = *(const f32x4*)&zT[(size_t)o * MTOT + bn];
#pragma unroll
    for (int j = 0; j < 4; ++j) {
      float hc = tanhf(p0[j] + p1[j]);
      float s0 = st[o][bl + j];
      st[o][bl + j] = (1.f - zv[j]) * s0 + zv[j] * hc;
    }
  }
  __syncthreads();
#pragma unroll
  for (int i = 0; i < 16; ++i) {
    int e = i * 256 + t;
    int bnr = e >> 6, oc = e & 63;
    out[(size_t)(bn0 + bnr) * 64 + oc] = st[oc][bnr];
  }
}

// ---------------------------------------------------------------
extern "C" void kernel_launch(void* const* d_in, const int* in_sizes, int n_in,
                              void* d_out, int out_size, void* d_ws, size_t ws_size,
                              hipStream_t stream) {
  const float* x     = (const float*)d_in[0];
  const float* state = (const float*)d_in[1];
  const float* E     = (const float*)d_in[2];
  const float* WpG   = (const float*)d_in[3];
  const float* BpG   = (const float*)d_in[4];
  const float* WpU   = (const float*)d_in[5];
  const float* BpU   = (const float*)d_in[6];
  float* out = (float*)d_out;

  char* p = (char*)d_ws;
  bf16*  Sbf   = (bf16*)p;  p += (size_t)NND * NND * 2;       // 8 MB
  bf16*  XT    = (bf16*)p;  p += (size_t)NPADC * NND * 2;     // 2.25 MB
  bf16*  candT = (bf16*)p;  p += (size_t)NPADC * NND * 2;     // 2.25 MB
  bf16*  Y1bf  = (bf16*)p;  p += (size_t)NPADC * NND * 2;     // 2.25 MB (also Z1)
  bf16*  Y2bf  = (bf16*)p;  p += (size_t)NPADC * NND * 2;     // 2.25 MB (also Z2)
  float* zT    = (float*)p; p += (size_t)64 * MTOT * 4;       // 4 MB
  bf16*  BTg   = (bf16*)p;  p += (size_t)128 * KEXP * 2;      // 832 KB
  bf16*  BTu   = (bf16*)p;  p += (size_t)64 * KEXP * 2;       // 416 KB
  float* P     = (float*)p; p += (size_t)2 * 128 * MTOT * 4;  // 16.8 MB (graph partials alias)

  dim3 b256(256), b512(512);
  dim3 gemmGrid(NND / 64, NPADC / 64, 2);

  prep_w_kernel<<<dim3(KEXP / 64, 2), b256, 0, stream>>>(WpG, BpG, BTg, 128);
  prep_w_kernel<<<dim3(KEXP / 64, 1), b256, 0, stream>>>(WpU, BpU, BTu, 64);
  adj_kernel<<<NND, b256, 0, stream>>>(E, Sbf);
  pack_xs_kernel<<<256, b256, 0, stream>>>(x, state, XT, candT);

  gemm_kernel<<<gemmGrid, b512, 0, stream>>>(Sbf, XT, P);
  reduce_kernel<<<NPADC * NND / 1024, b256, 0, stream>>>(P, Y1bf);
  gemm_kernel<<<gemmGrid, b512, 0, stream>>>(Sbf, Y1bf, P);
  reduce_kernel<<<NPADC * NND / 1024, b256, 0, stream>>>(P, Y2bf);
  wgemm_kernel<<<dim3(MTOT / 64, 2, 2), b512, 0, stream>>>(XT, Y1bf, Y2bf, E, BTg, 128, P);
  gate_epi<<<MTOT / 64, b256, 0, stream>>>(P, state, zT, candT);

  gemm_kernel<<<gemmGrid, b512, 0, stream>>>(Sbf, candT, P);
  reduce_kernel<<<NPADC * NND / 1024, b256, 0, stream>>>(P, Y1bf);
  gemm_kernel<<<gemmGrid, b512, 0, stream>>>(Sbf, Y1bf, P);
  reduce_kernel<<<NPADC * NND / 1024, b256, 0, stream>>>(P, Y2bf);
  wgemm_kernel<<<dim3(MTOT / 64, 1, 2), b512, 0, stream>>>(candT, Y1bf, Y2bf, E, BTu, 64, P);
  update_epi<<<MTOT / 64, b256, 0, stream>>>(P, state, zT, out);
}

// Round 4
// 188.904 us; speedup vs baseline: 1.9976x; 1.0148x over previous
//
#include <hip/hip_runtime.h>

typedef __bf16 bf16;
typedef __bf16 bf16x8 __attribute__((ext_vector_type(8)));
typedef __bf16 bf16x4 __attribute__((ext_vector_type(4)));
typedef float  f32x4  __attribute__((ext_vector_type(4)));

#define NND   2048      // nodes
#define DIMD  16        // embedding dim
#define NBB   8         // batch
#define NPADC 640       // padded panel rows (>= 528, mult of 128)
#define KEXP  3328      // expanded K: 208 ki-chunks * 16 d (198 real + bias + zeros)
#define MTOT  16384     // B*N

__device__ __forceinline__ float sigf(float v) { return 1.f / (1.f + __expf(-v)); }

__device__ __forceinline__ void gl_lds16(const bf16* g, bf16* l) {
  __builtin_amdgcn_global_load_lds(
      (const __attribute__((address_space(1))) void*)g,
      (__attribute__((address_space(3))) void*)l, 16, 0, 0);
}

// ---------------------------------------------------------------
// K1: S = softmax(relu(E E^T)) rows, bf16 out. 8 rows per block.
// E cached transposed in LDS once per block (kills 268MB L2 re-read).
// grid = 256
// ---------------------------------------------------------------
__global__ __launch_bounds__(256)
void adj_kernel(const float* __restrict__ E, bf16* __restrict__ Sbf) {
  int r0 = blockIdx.x * 8;
  int t = threadIdx.x;
  int lane = t & 63, w = t >> 6;
  __shared__ float Et[16][2048];
  __shared__ float red[2][4][8];
  for (int i = t; i < 8192; i += 256) {
    f32x4 v4 = *(const f32x4*)&E[(size_t)i * 4];
    int n = i >> 2, d0 = (i & 3) << 2;
    Et[d0 + 0][n] = v4.x; Et[d0 + 1][n] = v4.y;
    Et[d0 + 2][n] = v4.z; Et[d0 + 3][n] = v4.w;
  }
  __syncthreads();
  float er[8][16];
#pragma unroll
  for (int r = 0; r < 8; ++r)
#pragma unroll
    for (int d = 0; d < 16; ++d) er[r][d] = Et[d][r0 + r];   // broadcast reads

  float v[8][8];
  float mx[8];
#pragma unroll
  for (int r = 0; r < 8; ++r) mx[r] = 0.f;   // relu() >= 0
#pragma unroll
  for (int j = 0; j < 8; ++j) {
    int c = t + j * 256;
    float ec[16];
#pragma unroll
    for (int d = 0; d < 16; ++d) ec[d] = Et[d][c];           // stride-1, conflict-free
#pragma unroll
    for (int r = 0; r < 8; ++r) {
      float s = 0.f;
#pragma unroll
      for (int d = 0; d < 16; ++d) s += er[r][d] * ec[d];
      s = fmaxf(s, 0.f);
      v[r][j] = s;
      mx[r] = fmaxf(mx[r], s);
    }
  }
#pragma unroll
  for (int o = 32; o > 0; o >>= 1)
#pragma unroll
    for (int r = 0; r < 8; ++r) mx[r] = fmaxf(mx[r], __shfl_xor(mx[r], o, 64));
  if (lane == 0)
#pragma unroll
    for (int r = 0; r < 8; ++r) red[0][w][r] = mx[r];
  __syncthreads();
#pragma unroll
  for (int r = 0; r < 8; ++r)
    mx[r] = fmaxf(fmaxf(red[0][0][r], red[0][1][r]), fmaxf(red[0][2][r], red[0][3][r]));
  float sm[8];
#pragma unroll
  for (int r = 0; r < 8; ++r) sm[r] = 0.f;
#pragma unroll
  for (int j = 0; j < 8; ++j)
#pragma unroll
    for (int r = 0; r < 8; ++r) { v[r][j] = __expf(v[r][j] - mx[r]); sm[r] += v[r][j]; }
#pragma unroll
  for (int o = 32; o > 0; o >>= 1)
#pragma unroll
    for (int r = 0; r < 8; ++r) sm[r] += __shfl_xor(sm[r], o, 64);
  if (lane == 0)
#pragma unroll
    for (int r = 0; r < 8; ++r) red[1][w][r] = sm[r];
  __syncthreads();
#pragma unroll
  for (int r = 0; r < 8; ++r) {
    float inv = 1.f / (red[1][0][r] + red[1][1][r] + red[1][2][r] + red[1][3][r]);
#pragma unroll
    for (int j = 0; j < 8; ++j)
      Sbf[(size_t)(r0 + r) * NND + t + j * 256] = (bf16)(v[r][j] * inv);
  }
}

// ---------------------------------------------------------------
// K2: pack concat(x,state) transposed: XT[(b*66+c)][n] bf16.
// Also writes the x-rows (c<2) of candT.
// ---------------------------------------------------------------
__global__ __launch_bounds__(256)
void pack_xs_kernel(const float* __restrict__ x, const float* __restrict__ state,
                    bf16* __restrict__ XT, bf16* __restrict__ candT) {
  int b  = blockIdx.x >> 5;
  int n0 = (blockIdx.x & 31) * 64;
  int t  = threadIdx.x;
  __shared__ float tile[66][65];
  for (int idx = t; idx < 66 * 64; idx += 256) {
    int nn = idx / 66;
    int c  = idx - nn * 66;
    int bn = (b << 11) + n0 + nn;
    float v = (c < 2) ? x[bn * 2 + c] : state[(bn << 6) + c - 2];
    tile[c][nn] = v;
  }
  __syncthreads();
  for (int idx = t; idx < 66 * 64; idx += 256) {
    int c = idx >> 6;
    int nn = idx & 63;
    bf16 v = (bf16)tile[c][nn];
    size_t off = (size_t)(b * 66 + c) * NND + n0 + nn;
    XT[off] = v;
    if (c < 2) candT[off] = v;
  }
}

// ---------------------------------------------------------------
// K3: graph GEMM partials, m97-style. 128x128 tile, BK=64, 4 waves,
// acc 4x4/wave, global_load_lds(16B) linear staging, LDS dbuf 2-phase.
// P[z][c][n] = sum_{k in z-quarter} A[n][k]*BT[c][k]
// grid = (2048/128, NPADC/128, 4), 256 thr
// ---------------------------------------------------------------
__global__ __launch_bounds__(256)
void gemm_kernel(const bf16* __restrict__ A, const bf16* __restrict__ BT,
                 float* __restrict__ P) {
  __shared__ bf16 As[2][128 * 64];
  __shared__ bf16 Bs[2][128 * 64];
  int t = threadIdx.x;
  int m0 = blockIdx.x * 128;
  int c0 = blockIdx.y * 128;
  int z  = blockIdx.z;
  int lane = t & 63;
  int w = t >> 6;
  int wr = w >> 1, wc = w & 1;
  int row16 = lane & 15;
  int kq = (lane >> 4) << 3;

  f32x4 acc[4][4] = {};
  int kbase = z * 512;

  int srow = t >> 1;            // staging: slot = i*256+t -> row slot>>3
  (void)srow;

  // prologue stage into buf 0
  {
#pragma unroll
    for (int i = 0; i < 4; ++i) {
      int slot = i * 256 + t;
      int row = slot >> 3;
      int kc8 = (slot & 7) << 3;
      gl_lds16(A  + (size_t)(m0 + row) * NND + kbase + kc8, &As[0][slot * 8]);
      gl_lds16(BT + (size_t)(c0 + row) * NND + kbase + kc8, &Bs[0][slot * 8]);
    }
  }
  __syncthreads();

  int buf = 0;
  for (int s = 0; s < 8; ++s) {
    if (s < 7) {
      int k0 = kbase + (s + 1) * 64;
#pragma unroll
      for (int i = 0; i < 4; ++i) {
        int slot = i * 256 + t;
        int row = slot >> 3;
        int kc8 = (slot & 7) << 3;
        gl_lds16(A  + (size_t)(m0 + row) * NND + k0 + kc8, &As[buf ^ 1][slot * 8]);
        gl_lds16(BT + (size_t)(c0 + row) * NND + k0 + kc8, &Bs[buf ^ 1][slot * 8]);
      }
    }
#pragma unroll
    for (int kk2 = 0; kk2 < 64; kk2 += 32) {
      int kc = kk2 + kq;
      bf16x8 a[4], b[4];
#pragma unroll
      for (int mi = 0; mi < 4; ++mi)
        a[mi] = *(const bf16x8*)&As[buf][(wr * 64 + mi * 16 + row16) * 64 + kc];
#pragma unroll
      for (int ni = 0; ni < 4; ++ni)
        b[ni] = *(const bf16x8*)&Bs[buf][(wc * 64 + ni * 16 + row16) * 64 + kc];
#pragma unroll
      for (int mi = 0; mi < 4; ++mi)
#pragma unroll
        for (int ni = 0; ni < 4; ++ni)
          acc[mi][ni] = __builtin_amdgcn_mfma_f32_16x16x32_bf16(a[mi], b[ni], acc[mi][ni], 0, 0, 0);
    }
    __syncthreads();   // drains vmcnt (next-buf stage complete) + lgkm
    buf ^= 1;
  }

#pragma unroll
  for (int mi = 0; mi < 4; ++mi)
#pragma unroll
    for (int ni = 0; ni < 4; ++ni) {
      int nb = m0 + wr * 64 + mi * 16 + ((lane >> 4) << 2);
      int oc = c0 + wc * 64 + ni * 16 + (lane & 15);
      *(f32x4*)&P[((size_t)z * NPADC + oc) * NND + nb] = acc[mi][ni];
    }
}

// ---------------------------------------------------------------
// K3b: reduce 4 partials -> bf16.  Y[i] = bf16(P0+P1+P2+P3)
// grid = NPADC*NND/1024 = 1280
// ---------------------------------------------------------------
__global__ __launch_bounds__(256)
void reduce_kernel(const float* __restrict__ P, bf16* __restrict__ Y) {
  size_t i = ((size_t)blockIdx.x * 256 + threadIdx.x) * 4;
  const size_t PL = (size_t)NPADC * NND;
  f32x4 s = *(const f32x4*)&P[i];
  s += *(const f32x4*)&P[PL + i];
  s += *(const f32x4*)&P[2 * PL + i];
  s += *(const f32x4*)&P[3 * PL + i];
  *(bf16x4*)&Y[i] = __builtin_convertvector(s, bf16x4);
}

// ---------------------------------------------------------------
// K4: prep (merged gate+update).  B'T[o][ki*16+d] = Wp[d][ki/66][ki%66][o],
//     ki==198 -> bias, ki>198 -> 0.  grid = (KEXP/64, 3)
// ---------------------------------------------------------------
__global__ __launch_bounds__(256)
void prep_w_kernel(const float* __restrict__ WpG, const float* __restrict__ BpG,
                   const float* __restrict__ WpU, const float* __restrict__ BpU,
                   bf16* __restrict__ BTg, bf16* __restrict__ BTu) {
  __shared__ float tile[64][65];
  int which = blockIdx.y;
  const float* Wp; const float* Bp; bf16* BT; int ncols, o0;
  if (which < 2) { Wp = WpG; Bp = BpG; BT = BTg; ncols = 128; o0 = which * 64; }
  else           { Wp = WpU; Bp = BpU; BT = BTu; ncols = 64;  o0 = 0; }
  int k0 = blockIdx.x * 64;
  int t = threadIdx.x;
  for (int idx = t; idx < 4096; idx += 256) {
    int kr = idx >> 6, oc = idx & 63;
    int kp = k0 + kr;
    int ki = kp >> 4, d = kp & 15;
    float v;
    if (ki < 198) {
      int kc3 = ki / 66;
      int i = ki - kc3 * 66;
      v = Wp[(size_t)((d * 3 + kc3) * 66 + i) * ncols + o0 + oc];
    } else if (ki == 198) {
      v = Bp[d * ncols + o0 + oc];
    } else {
      v = 0.f;
    }
    tile[kr][oc] = v;
  }
  __syncthreads();
  for (int idx = t; idx < 4096; idx += 256) {
    int orow = idx >> 6, kc = idx & 63;
    BT[(size_t)(o0 + orow) * KEXP + k0 + kc] = (bf16)tile[kc][orow];
  }
}

// ---------------------------------------------------------------
// K5: expansion GEMM partials. P[z][oc][bn] over K-half z.
// A'[bn][ki*16+d] = xg(bn,ki)*E[n][d] built in LDS.
// 512 thr, 8 waves (2 K-groups x 4 quads). grid = (MTOT/64, ncols/64, 2)
// ---------------------------------------------------------------
__global__ __launch_bounds__(512, 6)
void wgemm_kernel(const bf16* __restrict__ XTsrc, const bf16* __restrict__ Y1src,
                  const bf16* __restrict__ Y2src, const float* __restrict__ E,
                  const bf16* __restrict__ BT, int ncols, float* __restrict__ P) {
  __shared__ bf16 As[64][136];
  __shared__ bf16 Bs[64][136];
  int t = threadIdx.x;
  int m0 = blockIdx.x * 64;
  int c0 = blockIdx.y * 64;
  int z  = blockIdx.z;
  int r  = t & 63;
  int kk = t >> 6;            // 0..7 (wave-uniform)
  int bn = m0 + r;
  int b  = bn >> 11, n = bn & 2047;
  const float4* ep = (const float4*)(E + n * 16);
  float4 e0 = ep[0], e1 = ep[1], e2 = ep[2], e3 = ep[3];
  int srow = t >> 3;          // 0..63
  int scol = (t & 7) << 3;
  int lane = t & 63;
  int w = t >> 6;
  int kg = w >> 2, quad = w & 3;
  int wr = quad >> 1, wc = quad & 1;
  int row16 = lane & 15;
  int kq = (lane >> 4) << 3;

  f32x4 acc[2][2] = {};
  int kbase = z * (KEXP / 2);

  for (int s = 0; s < 13; ++s) {
    int k0 = kbase + s * 128;
    int ki = (k0 >> 4) + kk;
    float xv;
    if (ki < 66) {
      xv = (float)XTsrc[(size_t)(b * 66 + ki) * NND + n];
    } else if (ki < 132) {
      xv = (float)Y1src[(size_t)(b * 66 + ki - 66) * NND + n];
    } else if (ki < 198) {
      size_t off = (size_t)(b * 66 + ki - 132) * NND + n;
      xv = 2.f * (float)Y2src[off] - (float)XTsrc[off];
    } else {
      xv = (ki == 198) ? 1.f : 0.f;
    }
    bf16x8 b0r = *(const bf16x8*)&BT[(size_t)(c0 + srow) * KEXP + k0 + scol];
    bf16x8 b1r = *(const bf16x8*)&BT[(size_t)(c0 + srow) * KEXP + k0 + 64 + scol];
    __syncthreads();
    f32x4 q0 = { xv*e0.x, xv*e0.y, xv*e0.z, xv*e0.w };
    f32x4 q1 = { xv*e1.x, xv*e1.y, xv*e1.z, xv*e1.w };
    f32x4 q2 = { xv*e2.x, xv*e2.y, xv*e2.z, xv*e2.w };
    f32x4 q3 = { xv*e3.x, xv*e3.y, xv*e3.z, xv*e3.w };
    *(bf16x4*)&As[r][kk*16 + 0]  = __builtin_convertvector(q0, bf16x4);
    *(bf16x4*)&As[r][kk*16 + 4]  = __builtin_convertvector(q1, bf16x4);
    *(bf16x4*)&As[r][kk*16 + 8]  = __builtin_convertvector(q2, bf16x4);
    *(bf16x4*)&As[r][kk*16 + 12] = __builtin_convertvector(q3, bf16x4);
    *(bf16x8*)&Bs[srow][scol]      = b0r;
    *(bf16x8*)&Bs[srow][64 + scol] = b1r;
    __syncthreads();
#pragma unroll
    for (int kk2 = 0; kk2 < 64; kk2 += 32) {
      int kc = kg * 64 + kk2 + kq;
      bf16x8 a0 = *(const bf16x8*)&As[wr*32 + row16][kc];
      bf16x8 a1 = *(const bf16x8*)&As[wr*32 + 16 + row16][kc];
      bf16x8 bb0 = *(const bf16x8*)&Bs[wc*32 + row16][kc];
      bf16x8 bb1 = *(const bf16x8*)&Bs[wc*32 + 16 + row16][kc];
      acc[0][0] = __builtin_amdgcn_mfma_f32_16x16x32_bf16(a0, bb0, acc[0][0], 0,0,0);
      acc[0][1] = __builtin_amdgcn_mfma_f32_16x16x32_bf16(a0, bb1, acc[0][1], 0,0,0);
      acc[1][0] = __builtin_amdgcn_mfma_f32_16x16x32_bf16(a1, bb0, acc[1][0], 0,0,0);
      acc[1][1] = __builtin_amdgcn_mfma_f32_16x16x32_bf16(a1, bb1, acc[1][1], 0,0,0);
    }
  }

  __syncthreads();
  float* red = (float*)&As[0][0];
  if (kg == 1) {
#pragma unroll
    for (int mi = 0; mi < 2; ++mi)
#pragma unroll
      for (int ni = 0; ni < 2; ++ni)
        *(f32x4*)&red[(((quad*2 + mi)*2 + ni)*64 + lane)*4] = acc[mi][ni];
  }
  __syncthreads();
  if (kg == 0) {
#pragma unroll
    for (int mi = 0; mi < 2; ++mi)
#pragma unroll
      for (int ni = 0; ni < 2; ++ni) {
        f32x4 v = acc[mi][ni] + *(const f32x4*)&red[(((quad*2 + mi)*2 + ni)*64 + lane)*4];
        int nb = m0 + wr*32 + mi*16 + ((lane >> 4) << 2);
        int oc = c0 + wc*32 + ni*16 + (lane & 15);
        *(f32x4*)&P[((size_t)z * ncols + oc) * MTOT + nb] = v;
      }
  }
}

// ---------------------------------------------------------------
// K6: gate epilogue. zT[h][bn] = sig(P0z+P1z); candT[.][n] = sig(P0r+P1r)*state
// grid = MTOT/64
// ---------------------------------------------------------------
__global__ __launch_bounds__(256)
void gate_epi(const float* __restrict__ P, const float* __restrict__ state,
              float* __restrict__ zT, bf16* __restrict__ candT) {
  __shared__ float st[64][65];
  int bn0 = blockIdx.x * 64;
  int t = threadIdx.x;
#pragma unroll
  for (int i = 0; i < 16; ++i) {
    int e = i * 256 + t;
    int bnr = e >> 6, hc = e & 63;
    st[hc][bnr] = state[(size_t)(bn0 + bnr) * 64 + hc];
  }
  __syncthreads();
#pragma unroll
  for (int i = 0; i < 4; ++i) {
    int pr = i * 256 + t;
    int h = pr >> 4, bl = (pr & 15) * 4;
    int bn = bn0 + bl;
    f32x4 p0z = *(const f32x4*)&P[(size_t)h * MTOT + bn];
    f32x4 p1z = *(const f32x4*)&P[(size_t)(128 + h) * MTOT + bn];
    f32x4 p0r = *(const f32x4*)&P[(size_t)(64 + h) * MTOT + bn];
    f32x4 p1r = *(const f32x4*)&P[(size_t)(192 + h) * MTOT + bn];
    f32x4 zv; bf16x4 cv;
#pragma unroll
    for (int j = 0; j < 4; ++j) {
      zv[j] = sigf(p0z[j] + p1z[j]);
      float rv = sigf(p0r[j] + p1r[j]) * st[h][bl + j];
      cv[j] = (bf16)rv;
    }
    *(f32x4*)&zT[(size_t)h * MTOT + bn] = zv;
    int b = bn >> 11, n = bn & 2047;
    *(bf16x4*)&candT[(size_t)(b * 66 + 2 + h) * NND + n] = cv;
  }
}

// ---------------------------------------------------------------
// K7: update epilogue. out[bn][o] = (1-z)*state + z*tanh(P0+P1)
// grid = MTOT/64
// ---------------------------------------------------------------
__global__ __launch_bounds__(256)
void update_epi(const float* __restrict__ P, const float* __restrict__ state,
                const float* __restrict__ zT, float* __restrict__ out) {
  __shared__ float st[64][65];
  int bn0 = blockIdx.x * 64;
  int t = threadIdx.x;
#pragma unroll
  for (int i = 0; i < 16; ++i) {
    int e = i * 256 + t;
    int bnr = e >> 6, oc = e & 63;
    st[oc][bnr] = state[(size_t)(bn0 + bnr) * 64 + oc];
  }
  __syncthreads();
#pragma unroll
  for (int i = 0; i < 4; ++i) {
    int pr = i * 256 + t;
    int o = pr >> 4, bl = (pr & 15) * 4;
    int bn = bn0 + bl;
    f32x4 p0 = *(const f32x4*)&P[(size_t)o * MTOT + bn];
    f32x4 p1 = *(const f32x4*)&P[(size_t)(64 + o) * MTOT + bn];
    f32x4 zv = *(const f32x4*)&zT[(size_t)o * MTOT + bn];
#pragma unroll
    for (int j = 0; j < 4; ++j) {
      float hc = tanhf(p0[j] + p1[j]);
      float s0 = st[o][bl + j];
      st[o][bl + j] = (1.f - zv[j]) * s0 + zv[j] * hc;
    }
  }
  __syncthreads();
#pragma unroll
  for (int i = 0; i < 16; ++i) {
    int e = i * 256 + t;
    int bnr = e >> 6, oc = e & 63;
    out[(size_t)(bn0 + bnr) * 64 + oc] = st[oc][bnr];
  }
}

// ---------------------------------------------------------------
extern "C" void kernel_launch(void* const* d_in, const int* in_sizes, int n_in,
                              void* d_out, int out_size, void* d_ws, size_t ws_size,
                              hipStream_t stream) {
  const float* x     = (const float*)d_in[0];
  const float* state = (const float*)d_in[1];
  const float* E     = (const float*)d_in[2];
  const float* WpG   = (const float*)d_in[3];
  const float* BpG   = (const float*)d_in[4];
  const float* WpU   = (const float*)d_in[5];
  const float* BpU   = (const float*)d_in[6];
  float* out = (float*)d_out;

  char* p = (char*)d_ws;
  bf16*  Sbf   = (bf16*)p;  p += (size_t)NND * NND * 2;       // 8 MB
  bf16*  XT    = (bf16*)p;  p += (size_t)NPADC * NND * 2;     // 2.5 MB
  bf16*  candT = (bf16*)p;  p += (size_t)NPADC * NND * 2;     // 2.5 MB
  bf16*  Y1bf  = (bf16*)p;  p += (size_t)NPADC * NND * 2;     // 2.5 MB (also Z1)
  bf16*  Y2bf  = (bf16*)p;  p += (size_t)NPADC * NND * 2;     // 2.5 MB (also Z2)
  float* zT    = (float*)p; p += (size_t)64 * MTOT * 4;       // 4 MB
  bf16*  BTg   = (bf16*)p;  p += (size_t)128 * KEXP * 2;      // 832 KB
  bf16*  BTu   = (bf16*)p;  p += (size_t)64 * KEXP * 2;       // 416 KB
  float* P     = (float*)p; p += (size_t)4 * NPADC * NND * 4; // 21 MB (wgemm partials alias)

  dim3 b256(256), b512(512);
  dim3 gemmGrid(NND / 128, NPADC / 128, 4);
  int redGrid = NPADC * NND / 1024;

  prep_w_kernel<<<dim3(KEXP / 64, 3), b256, 0, stream>>>(WpG, BpG, WpU, BpU, BTg, BTu);
  adj_kernel<<<256, b256, 0, stream>>>(E, Sbf);
  pack_xs_kernel<<<256, b256, 0, stream>>>(x, state, XT, candT);

  gemm_kernel<<<gemmGrid, b256, 0, stream>>>(Sbf, XT, P);
  reduce_kernel<<<redGrid, b256, 0, stream>>>(P, Y1bf);
  gemm_kernel<<<gemmGrid, b256, 0, stream>>>(Sbf, Y1bf, P);
  reduce_kernel<<<redGrid, b256, 0, stream>>>(P, Y2bf);
  wgemm_kernel<<<dim3(MTOT / 64, 2, 2), b512, 0, stream>>>(XT, Y1bf, Y2bf, E, BTg, 128, P);
  gate_epi<<<MTOT / 64, b256, 0, stream>>>(P, state, zT, candT);

  gemm_kernel<<<gemmGrid, b256, 0, stream>>>(Sbf, candT, P);
  reduce_kernel<<<redGrid, b256, 0, stream>>>(P, Y1bf);
  gemm_kernel<<<gemmGrid, b256, 0, stream>>>(Sbf, Y1bf, P);
  reduce_kernel<<<redGrid, b256, 0, stream>>>(P, Y2bf);
  wgemm_kernel<<<dim3(MTOT / 64, 1, 2), b512, 0, stream>>>(candT, Y1bf, Y2bf, E, BTu, 64, P);
  update_epi<<<MTOT / 64, b256, 0, stream>>>(P, state, zT, out);
}